// Round 3
// baseline (1622.958 us; speedup 1.0000x reference)
//
#include <hip/hip_runtime.h>
#include <hip/hip_bf16.h>
#include <math.h>

#define CDIM 91
#define DDIM 256

// ---------- helpers ----------
__device__ __forceinline__ float wave_sum(float v) {
    #pragma unroll
    for (int off = 32; off > 0; off >>= 1)
        v += __shfl_xor(v, off, 64);
    return v;
}

// block-wide sum over 128 threads using provided LDS buffer
__device__ __forceinline__ float block_sum128(volatile float* red, int t, float v) {
    red[t] = v;
    __syncthreads();
    for (int s = 64; s > 0; s >>= 1) {
        if (t < s) red[t] += red[t + s];
        __syncthreads();
    }
    float r = red[0];
    __syncthreads();
    return r;
}

// ---------- k1: fused norm + histogram + scatter-accumulate ----------
// One wave per row: 64 lanes x float4 = 256 floats. The wave computes the
// row's L2 norm in-register (saves the separate k0 pass over 256 MB),
// writes inv[r], bumps the label histogram, and scatters f/||f|| into the
// per-block LDS accumulator [C][D].
__global__ __launch_bounds__(256) void k1_fused(
    const float* __restrict__ f, const int* __restrict__ labels,
    float* __restrict__ inv, unsigned int* __restrict__ cnt,
    float* __restrict__ seg, int M)
{
    __shared__ float acc[CDIM * DDIM];   // 93184 B (gfx950 LDS = 160 KB)
    __shared__ unsigned int hist[CDIM];
    for (int t = threadIdx.x; t < CDIM * DDIM; t += 256) acc[t] = 0.0f;
    for (int t = threadIdx.x; t < CDIM; t += 256) hist[t] = 0;
    __syncthreads();
    const int sub  = threadIdx.x >> 6;   // wave id within block (row selector)
    const int lane = threadIdx.x & 63;   // float4 column group
    int rows = ((M / 4) + gridDim.x - 1) / gridDim.x * 4;
    const int r0 = blockIdx.x * rows;
    const int r1 = min(M, r0 + rows);
    for (int r = r0 + sub; r < r1; r += 4) {
        const float4 v = *reinterpret_cast<const float4*>(f + (size_t)r * DDIM + lane * 4);
        const float ss = wave_sum(v.x * v.x + v.y * v.y + v.z * v.z + v.w * v.w);
        const float iv = 1.0f / fmaxf(sqrtf(ss), 1e-12f);
        const int   c  = labels[r];      // wave-uniform (broadcast load)
        if (lane == 0) {
            inv[r] = iv;
            atomicAdd(&hist[c], 1u);
        }
        float* a = &acc[c * DDIM + lane * 4];
        atomicAdd(a + 0, v.x * iv);      // LDS atomics; cross-wave label clashes possible
        atomicAdd(a + 1, v.y * iv);
        atomicAdd(a + 2, v.z * iv);
        atomicAdd(a + 3, v.w * iv);
    }
    __syncthreads();
    for (int idx = threadIdx.x; idx < CDIM * DDIM; idx += 256)
        unsafeAtomicAdd(&seg[idx], acc[idx]);
    for (int t = threadIdx.x; t < CDIM; t += 256)
        if (hist[t]) atomicAdd(&cnt[t], hist[t]);
}

// ---------- k2: per-class EMA update + normalized prototypes ----------
__global__ __launch_bounds__(256) void k2_update(
    const float* __restrict__ seg, const unsigned int* __restrict__ cnt,
    const float* __restrict__ proto, const int* __restrict__ pinit,  // bool passed as int32
    const int* __restrict__ pcount, const float* __restrict__ pvar,
    const int* __restrict__ stepp,
    float* __restrict__ pn, float* __restrict__ ncnt, float* __restrict__ nvar,
    int* __restrict__ ninit)
{
    const int wid = threadIdx.x >> 6, lane = threadIdx.x & 63;
    const int c = blockIdx.x * 4 + wid;
    if (c >= CDIM) return;
    const int d0 = lane * 4;
    const float4 s = *reinterpret_cast<const float4*>(seg + c * DDIM + d0);
    const float4 p = *reinterpret_cast<const float4*>(proto + c * DDIM + d0);
    const float cntf = (float)cnt[c];
    const bool has  = cntf > 0.0f;
    const bool init = pinit[c] != 0;
    const double prog = fmin(1.0, (double)stepp[0] / 2000.0);   // WARMUP*10
    const double md = 0.99 + (0.999 - 0.99) * prog;
    const float m  = (float)md;
    const float om = (float)(1.0 - md);
    const float dn = fmaxf(cntf, 1.0f);
    const float mx = s.x / dn, my = s.y / dn, mz = s.z / dn, mw = s.w / dn;
    const float ex = m * p.x + om * mx, ey = m * p.y + om * my;
    const float ez = m * p.z + om * mz, ew = m * p.w + om * mw;
    const float nx = has ? (init ? ex : mx) : p.x;
    const float ny = has ? (init ? ey : my) : p.y;
    const float nz = has ? (init ? ez : mz) : p.z;
    const float nw = has ? (init ? ew : mw) : p.w;
    const float dx = mx - p.x, dy = my - p.y, dz = mz - p.z, dw = mw - p.w;
    const float dsum = wave_sum(dx * dx + dy * dy + dz * dz + dw * dw);
    const float nsum = wave_sum(nx * nx + ny * ny + nz * nz + nw * nw);
    const float mag = sqrtf(dsum);
    const float nrm = fmaxf(sqrtf(nsum), 1e-12f);
    float4 o;
    o.x = nx / nrm; o.y = ny / nrm; o.z = nz / nrm; o.w = nw / nrm;
    *reinterpret_cast<float4*>(pn + c * DDIM + d0) = o;
    if (lane == 0) {
        ncnt[c]  = (float)(pcount[c] + (has ? 1 : 0));
        nvar[c]  = (has && init) ? (0.99f * pvar[c] + 0.01f * mag) : pvar[c];
        ninit[c] = (init || has) ? 1 : 0;
    }
}

// ---------- k3: per-class weights (mmean collapses to class sums) ----------
__global__ __launch_bounds__(128) void k3_weights(
    const unsigned int* __restrict__ cnt, const float* __restrict__ ncnt,
    const float* __restrict__ nvar, const int* __restrict__ ninit,
    float* __restrict__ wv, float* __restrict__ nvp, float* __restrict__ npr)
{
    __shared__ float red[128];
    const int t = threadIdx.x;
    float n_c = 0.0f, fc = 0.0f, qc = 0.0f, validc = 0.0f, initc = 0.0f;
    if (t < CDIM) {
        n_c = (float)cnt[t];
        initc = ninit[t] ? 1.0f : 0.0f;
        validc = initc;
        fc = 1.0f / fmaxf(ncnt[t], 1.0f);
        qc = 1.0f / fmaxf(nvar[t], 1e-4f);
    }
    const float nv    = fmaxf(block_sum128(red, t, n_c * validc), 1e-8f);
    const float meanf = block_sum128(red, t, n_c * validc * fc) / nv;
    const float meanq = block_sum128(red, t, n_c * validc * qc) / nv;
    const float fn = fminf(fc / fmaxf(meanf, 1e-8f), 5.0f);
    const float qn = fminf(qc / fmaxf(meanq, 1e-8f), 5.0f);
    const float w  = fn * qn;
    const float meanw = block_sum128(red, t, n_c * validc * w) / nv;
    const float wn = w / fmaxf(meanw, 1e-8f);
    if (t < CDIM) wv[t] = wn * validc;
    const float ki = block_sum128(red, t, initc);
    if (t == 0) { nvp[0] = nv; npr[0] = ki * (ki - 1.0f) * 0.5f; }
}

// ---------- k4: repulsion (upper-tri pairs of proto cosine sims) ----------
__global__ __launch_bounds__(256) void k4_rep(
    const float* __restrict__ pn, const int* __restrict__ ninit,
    float* __restrict__ reps)
{
    const int wid = threadIdx.x >> 6, lane = threadIdx.x & 63;
    const int gw = blockIdx.x * 4 + wid;
    const int nw = gridDim.x * 4;
    for (int p = gw; p < CDIM * CDIM; p += nw) {
        const int i = p / CDIM, j = p % CDIM;
        if (i >= j) continue;
        if (!(ninit[i] && ninit[j])) continue;
        const float4 a = *reinterpret_cast<const float4*>(pn + i * DDIM + lane * 4);
        const float4 b = *reinterpret_cast<const float4*>(pn + j * DDIM + lane * 4);
        float d = a.x * b.x + a.y * b.y + a.z * b.z + a.w * b.w;
        d = wave_sum(d);
        if (lane == 0) unsafeAtomicAdd(reps, fmaxf(d, 0.0f));
    }
}

// ---------- k5: pull loss (thread-per-sample, 91 reg accumulators) ----------
__global__ __launch_bounds__(256) void k5_loss(
    const float* __restrict__ f, const int* __restrict__ labels,
    const float* __restrict__ pn, const float* __restrict__ inv,
    const float* __restrict__ wv, float* __restrict__ pull, int M)
{
    const int i = blockIdx.x * 256 + threadIdx.x;
    float contrib = 0.0f;
    if (i < M) {
        float acc[CDIM];
        #pragma unroll
        for (int c = 0; c < CDIM; ++c) acc[c] = 0.0f;
        const float* frow = f + (size_t)i * DDIM;
        for (int k = 0; k < DDIM; k += 8) {
            const float4 a = *reinterpret_cast<const float4*>(frow + k);
            const float4 b = *reinterpret_cast<const float4*>(frow + k + 4);
            #pragma unroll
            for (int c = 0; c < CDIM; ++c) {
                const float* pr = pn + c * DDIM + k;   // wave-uniform -> s_load
                acc[c] = fmaf(a.x, pr[0], acc[c]);
                acc[c] = fmaf(a.y, pr[1], acc[c]);
                acc[c] = fmaf(a.z, pr[2], acc[c]);
                acc[c] = fmaf(a.w, pr[3], acc[c]);
                acc[c] = fmaf(b.x, pr[4], acc[c]);
                acc[c] = fmaf(b.y, pr[5], acc[c]);
                acc[c] = fmaf(b.z, pr[6], acc[c]);
                acc[c] = fmaf(b.w, pr[7], acc[c]);
            }
        }
        const int lab = labels[i];
        const float scale = inv[i] * 10.0f;   // (1/tau) * 1/||f||
        float mx = -1e30f;
        #pragma unroll
        for (int c = 0; c < CDIM; ++c) { acc[c] *= scale; mx = fmaxf(mx, acc[c]); }
        float se = 0.0f, ll = 0.0f;
        #pragma unroll
        for (int c = 0; c < CDIM; ++c) {
            se += __expf(acc[c] - mx);
            ll = (c == lab) ? acc[c] : ll;
        }
        const float lse = mx + __logf(se);
        contrib = (lse - ll) * wv[lab];
    }
    contrib = wave_sum(contrib);
    if ((threadIdx.x & 63) == 0) unsafeAtomicAdd(pull, contrib);
}

// ---------- k6: combine ----------
__global__ void k6_final(const float* __restrict__ pull, const float* __restrict__ nvp,
                         const float* __restrict__ reps, const float* __restrict__ npr,
                         float* __restrict__ out)
{
    const float np = npr[0];
    const float rep = (np > 0.0f) ? (reps[0] / fmaxf(np, 1.0f)) : 0.0f;
    out[0] = pull[0] / nvp[0] + 0.1f * rep;
}

extern "C" void kernel_launch(void* const* d_in, const int* in_sizes, int n_in,
                              void* d_out, int out_size, void* d_ws, size_t ws_size,
                              hipStream_t stream)
{
    const float* features = (const float*)d_in[0];
    const int*   labels   = (const int*)d_in[1];
    const float* proto    = (const float*)d_in[2];
    const int*   pinit    = (const int*)d_in[3];   // bool array arrives as int32
    const int*   pcount   = (const int*)d_in[4];
    const float* pvar     = (const float*)d_in[5];
    const int*   stepp    = (const int*)d_in[6];
    float*       out      = (float*)d_out;
    const int M = in_sizes[0] / DDIM;

    // workspace layout (floats). Zero leading region with a single memset.
    float* W = (float*)d_ws;
    float*        seg  = W;                                   // C*D
    unsigned int* cnt  = (unsigned int*)(seg + CDIM * DDIM);  // C
    float*        pull = (float*)(cnt + CDIM);                // 1
    float*        reps = pull + 1;                            // 1
    float*        inv  = reps + 1;                            // M
    float*        pn   = inv + M;                             // C*D
    float*        wv   = pn + CDIM * DDIM;                    // C
    float*        ncnt = wv + CDIM;                           // C
    float*        nvar = ncnt + CDIM;                         // C
    float*        nvp  = nvar + CDIM;                         // 1
    float*        npr  = nvp + 1;                             // 1
    int*          nini = (int*)(npr + 1);                     // C

    hipMemsetAsync(seg, 0, (CDIM * DDIM + CDIM + 2) * sizeof(float), stream);

    k1_fused<<<256, 256, 0, stream>>>(features, labels, inv, cnt, seg, M);
    k2_update<<<(CDIM + 3) / 4, 256, 0, stream>>>(seg, cnt, proto, pinit, pcount,
                                                  pvar, stepp, pn, ncnt, nvar, nini);
    k3_weights<<<1, 128, 0, stream>>>(cnt, ncnt, nvar, nini, wv, nvp, npr);
    k4_rep<<<64, 256, 0, stream>>>(pn, nini, reps);
    k5_loss<<<(M + 255) / 256, 256, 0, stream>>>(features, labels, pn, inv, wv, pull, M);
    k6_final<<<1, 1, 0, stream>>>(pull, nvp, reps, npr, out);
}

// Round 5
// 1138.255 us; speedup vs baseline: 1.4258x; 1.4258x over previous
//
#include <hip/hip_runtime.h>
#include <hip/hip_bf16.h>
#include <math.h>
#include <stdint.h>

#define CDIM 91
#define DDIM 256
#define CPAD 96                 // 6 tiles of 16 classes
#define NFRAG 24576             // 6 tiles * 8 ksteps * 64 lanes * 8 elems (bf16 each)

typedef float f32x4 __attribute__((ext_vector_type(4)));
typedef short v8s   __attribute__((ext_vector_type(8)));   // 8 bf16 in 4 VGPRs

// ---------- helpers ----------
__device__ __forceinline__ float wave_sum(float v) {
    #pragma unroll
    for (int off = 32; off > 0; off >>= 1)
        v += __shfl_xor(v, off, 64);
    return v;
}

__device__ __forceinline__ float block_sum128(volatile float* red, int t, float v) {
    red[t] = v;
    __syncthreads();
    for (int s = 64; s > 0; s >>= 1) {
        if (t < s) red[t] += red[t + s];
        __syncthreads();
    }
    float r = red[0];
    __syncthreads();
    return r;
}

__device__ __forceinline__ unsigned short f2bf(float x) {   // RNE truncate f32->bf16
    union { float f; unsigned u; } a; a.f = x;
    unsigned r = a.u + 0x7fff + ((a.u >> 16) & 1);
    return (unsigned short)(r >> 16);
}
__device__ __forceinline__ float bf2f(unsigned short h) {
    union { unsigned u; float f; } a; a.u = ((unsigned)h) << 16; return a.f;
}

// ---------- k1: fused norm + histogram + scatter (16 waves/block) ----------
// Lane owns columns {lane, lane+64, lane+128, lane+192}: dword loads stay fully
// coalesced (64 lanes x 4B consecutive) and the 4 LDS atomics are conflict-free
// (bank = lane%32, 2 lanes/bank which is free).
__global__ __launch_bounds__(1024) void k1_fused(
    const float* __restrict__ f, const int* __restrict__ labels,
    float* __restrict__ inv, unsigned int* __restrict__ cnt,
    float* __restrict__ seg, int M)
{
    __shared__ float acc[CDIM * DDIM];   // 93184 B
    __shared__ unsigned int hist[CDIM];
    for (int t = threadIdx.x; t < CDIM * DDIM; t += 1024) acc[t] = 0.0f;
    if (threadIdx.x < CDIM) hist[threadIdx.x] = 0;
    __syncthreads();
    const int sub  = threadIdx.x >> 6;   // wave 0..15
    const int lane = threadIdx.x & 63;
    const int rows = M / gridDim.x;      // 1024
    const int r0 = blockIdx.x * rows, r1 = r0 + rows;
    for (int r = r0 + sub; r < r1; r += 16) {
        const float* frow = f + (size_t)r * DDIM;
        const float v0 = frow[lane], v1 = frow[lane + 64];
        const float v2 = frow[lane + 128], v3 = frow[lane + 192];
        const float ss = wave_sum(v0*v0 + v1*v1 + v2*v2 + v3*v3);
        const float iv = 1.0f / fmaxf(sqrtf(ss), 1e-12f);
        const int c = labels[r];         // wave-uniform
        if (lane == 0) { inv[r] = iv; atomicAdd(&hist[c], 1u); }
        float* a = acc + c * DDIM;
        atomicAdd(a + lane,       v0 * iv);
        atomicAdd(a + lane + 64,  v1 * iv);
        atomicAdd(a + lane + 128, v2 * iv);
        atomicAdd(a + lane + 192, v3 * iv);
    }
    __syncthreads();
    for (int i = threadIdx.x; i < CDIM * DDIM; i += 1024)
        unsafeAtomicAdd(&seg[i], acc[i]);
    if (threadIdx.x < CDIM && hist[threadIdx.x])
        atomicAdd(&cnt[threadIdx.x], hist[threadIdx.x]);
}

// ---------- k2: per-class EMA update + normalized prototypes ----------
__global__ __launch_bounds__(256) void k2_update(
    const float* __restrict__ seg, const unsigned int* __restrict__ cnt,
    const float* __restrict__ proto, const int* __restrict__ pinit,  // bool as int32
    const int* __restrict__ pcount, const float* __restrict__ pvar,
    const int* __restrict__ stepp,
    float* __restrict__ pn, float* __restrict__ ncnt, float* __restrict__ nvar,
    int* __restrict__ ninit)
{
    const int wid = threadIdx.x >> 6, lane = threadIdx.x & 63;
    const int c = blockIdx.x * 4 + wid;
    if (c >= CDIM) return;
    const int d0 = lane * 4;
    const float4 s = *reinterpret_cast<const float4*>(seg + c * DDIM + d0);
    const float4 p = *reinterpret_cast<const float4*>(proto + c * DDIM + d0);
    const float cntf = (float)cnt[c];
    const bool has  = cntf > 0.0f;
    const bool init = pinit[c] != 0;
    const double prog = fmin(1.0, (double)stepp[0] / 2000.0);
    const double md = 0.99 + (0.999 - 0.99) * prog;
    const float m  = (float)md, om = (float)(1.0 - md);
    const float dn = fmaxf(cntf, 1.0f);
    const float mx = s.x / dn, my = s.y / dn, mz = s.z / dn, mw = s.w / dn;
    const float ex = m * p.x + om * mx, ey = m * p.y + om * my;
    const float ez = m * p.z + om * mz, ew = m * p.w + om * mw;
    const float nx = has ? (init ? ex : mx) : p.x;
    const float ny = has ? (init ? ey : my) : p.y;
    const float nz = has ? (init ? ez : mz) : p.z;
    const float nw = has ? (init ? ew : mw) : p.w;
    const float dx = mx - p.x, dy = my - p.y, dz = mz - p.z, dw = mw - p.w;
    const float dsum = wave_sum(dx*dx + dy*dy + dz*dz + dw*dw);
    const float nsum = wave_sum(nx*nx + ny*ny + nz*nz + nw*nw);
    const float mag = sqrtf(dsum);
    const float nrm = fmaxf(sqrtf(nsum), 1e-12f);
    float4 o; o.x = nx/nrm; o.y = ny/nrm; o.z = nz/nrm; o.w = nw/nrm;
    *reinterpret_cast<float4*>(pn + c * DDIM + d0) = o;
    if (lane == 0) {
        ncnt[c]  = (float)(pcount[c] + (has ? 1 : 0));
        nvar[c]  = (has && init) ? (0.99f * pvar[c] + 0.01f * mag) : pvar[c];
        ninit[c] = (init || has) ? 1 : 0;
    }
}

// ---------- k2b: prototypes -> fragment-ordered bf16 hi/lo arrays ----------
// Element (t,s,lane,j): class c = t*16+(lane&15), k = s*32+(lane>>4)*8+j.
// Linear layout so k5's LDS staging is a straight copy and per-lane ds_read_b128
// is conflict-free. Classes >= 91 padded with zeros (masked in epilogue).
__global__ __launch_bounds__(64) void k2b_bfrag(
    const float* __restrict__ pn, unsigned short* __restrict__ bf)
{
    const int t = blockIdx.x >> 3, s = blockIdx.x & 7;
    const int l = threadIdx.x;
    const int c = t * 16 + (l & 15);
    const int k0 = s * 32 + (l >> 4) * 8;
    float v[8];
    if (c < CDIM) {
        const float4 x = *reinterpret_cast<const float4*>(pn + c * DDIM + k0);
        const float4 y = *reinterpret_cast<const float4*>(pn + c * DDIM + k0 + 4);
        v[0]=x.x; v[1]=x.y; v[2]=x.z; v[3]=x.w; v[4]=y.x; v[5]=y.y; v[6]=y.z; v[7]=y.w;
    } else {
        #pragma unroll
        for (int j = 0; j < 8; ++j) v[j] = 0.0f;
    }
    union { unsigned short u[8]; v8s vv; } H, L;
    #pragma unroll
    for (int j = 0; j < 8; ++j) {
        H.u[j] = f2bf(v[j]);
        L.u[j] = f2bf(v[j] - bf2f(H.u[j]));
    }
    const int base = ((t * 8 + s) * 64 + l) * 8;
    *reinterpret_cast<v8s*>(bf + base)         = H.vv;
    *reinterpret_cast<v8s*>(bf + NFRAG + base) = L.vv;
}

// ---------- k3: per-class weights ----------
__global__ __launch_bounds__(128) void k3_weights(
    const unsigned int* __restrict__ cnt, const float* __restrict__ ncnt,
    const float* __restrict__ nvar, const int* __restrict__ ninit,
    float* __restrict__ wv, float* __restrict__ nvp, float* __restrict__ npr)
{
    __shared__ float red[128];
    const int t = threadIdx.x;
    float n_c = 0.0f, fc = 0.0f, qc = 0.0f, validc = 0.0f, initc = 0.0f;
    if (t < CDIM) {
        n_c = (float)cnt[t];
        initc = ninit[t] ? 1.0f : 0.0f;
        validc = initc;
        fc = 1.0f / fmaxf(ncnt[t], 1.0f);
        qc = 1.0f / fmaxf(nvar[t], 1e-4f);
    }
    const float nv    = fmaxf(block_sum128(red, t, n_c * validc), 1e-8f);
    const float meanf = block_sum128(red, t, n_c * validc * fc) / nv;
    const float meanq = block_sum128(red, t, n_c * validc * qc) / nv;
    const float fn = fminf(fc / fmaxf(meanf, 1e-8f), 5.0f);
    const float qn = fminf(qc / fmaxf(meanq, 1e-8f), 5.0f);
    const float w  = fn * qn;
    const float meanw = block_sum128(red, t, n_c * validc * w) / nv;
    const float wn = w / fmaxf(meanw, 1e-8f);
    if (t < CDIM) wv[t] = wn * validc;
    const float ki = block_sum128(red, t, initc);
    if (t == 0) { nvp[0] = nv; npr[0] = ki * (ki - 1.0f) * 0.5f; }
}

// ---------- k4: repulsion ----------
__global__ __launch_bounds__(256) void k4_rep(
    const float* __restrict__ pn, const int* __restrict__ ninit,
    float* __restrict__ reps)
{
    const int wid = threadIdx.x >> 6, lane = threadIdx.x & 63;
    const int gw = blockIdx.x * 4 + wid;
    const int nw = gridDim.x * 4;
    for (int p = gw; p < CDIM * CDIM; p += nw) {
        const int i = p / CDIM, j = p % CDIM;
        if (i >= j) continue;
        if (!(ninit[i] && ninit[j])) continue;
        const float4 a = *reinterpret_cast<const float4*>(pn + i * DDIM + lane * 4);
        const float4 b = *reinterpret_cast<const float4*>(pn + j * DDIM + lane * 4);
        float d = a.x*b.x + a.y*b.y + a.z*b.z + a.w*b.w;
        d = wave_sum(d);
        if (lane == 0) unsafeAtomicAdd(reps, fmaxf(d, 0.0f));
    }
}

// ---------- k5: pull loss via split-bf16 MFMA + fused softmax ----------
// f32 logits emulated as fHi*pHi + fHi*pLo + fLo*pHi (err ~2^-18 rel).
// Wave = 16 rows x 96 classes; block = 16 waves = 256 rows; persistent over 4 tiles.
__global__ __launch_bounds__(1024) void k5_mfma(
    const float* __restrict__ f, const int* __restrict__ labels,
    const unsigned short* __restrict__ bfg, const float* __restrict__ inv,
    const float* __restrict__ wv, float* __restrict__ pull, int M)
{
    __shared__ __align__(16) unsigned short bl[2 * NFRAG];   // 98304 B
    {   // stage fragment-ordered B (hi|lo) linearly: conflict-free, coalesced
        const float4* src = reinterpret_cast<const float4*>(bfg);
        float4* dst = reinterpret_cast<float4*>(bl);
        #pragma unroll
        for (int i = 0; i < 6; ++i)
            dst[threadIdx.x + i * 1024] = src[threadIdx.x + i * 1024];
    }
    __syncthreads();
    const int w = threadIdx.x >> 6, lane = threadIdx.x & 63;
    const int col0 = lane & 15, grp = lane >> 4;
    const int ntiles = M / 256;                       // 1024
    float contrib = 0.0f;

    for (int tile = blockIdx.x; tile < ntiles; tile += gridDim.x) {
        const int r0 = tile * 256 + w * 16;
        const float* frow = f + (size_t)(r0 + col0) * DDIM + grp * 8;
        f32x4 acc0 = {0,0,0,0}, acc1 = {0,0,0,0}, acc2 = {0,0,0,0};
        f32x4 acc3 = {0,0,0,0}, acc4 = {0,0,0,0}, acc5 = {0,0,0,0};
        #pragma unroll
        for (int s = 0; s < 8; ++s) {
            const float4 x = *reinterpret_cast<const float4*>(frow + s * 32);
            const float4 y = *reinterpret_cast<const float4*>(frow + s * 32 + 4);
            const float v[8] = {x.x, x.y, x.z, x.w, y.x, y.y, y.z, y.w};
            union { unsigned short u[8]; v8s vv; } AH, AL;
            #pragma unroll
            for (int j = 0; j < 8; ++j) {
                AH.u[j] = f2bf(v[j]);
                AL.u[j] = f2bf(v[j] - bf2f(AH.u[j]));
            }
            #pragma unroll
            for (int t = 0; t < 6; ++t) {
                const int off = ((t * 8 + s) * 64 + lane) * 8;
                const v8s BH = *reinterpret_cast<const v8s*>(bl + off);
                const v8s BL = *reinterpret_cast<const v8s*>(bl + NFRAG + off);
                f32x4 a = (t==0)?acc0:(t==1)?acc1:(t==2)?acc2:(t==3)?acc3:(t==4)?acc4:acc5;
                a = __builtin_amdgcn_mfma_f32_16x16x32_bf16(AH.vv, BH, a, 0, 0, 0);
                a = __builtin_amdgcn_mfma_f32_16x16x32_bf16(AH.vv, BL, a, 0, 0, 0);
                a = __builtin_amdgcn_mfma_f32_16x16x32_bf16(AL.vv, BH, a, 0, 0, 0);
                if (t==0) acc0=a; else if (t==1) acc1=a; else if (t==2) acc2=a;
                else if (t==3) acc3=a; else if (t==4) acc4=a; else acc5=a;
            }
        }
        // epilogue: C/D layout col=lane&15, row=(lane>>4)*4+reg  [m89]
        const int rbase = r0 + grp * 4;
        const float4 invv = *reinterpret_cast<const float4*>(inv + rbase);
        const int4   labv = *reinterpret_cast<const int4*>(labels + rbase);
        #pragma unroll
        for (int rg = 0; rg < 4; ++rg) {
            const float scale = ((const float*)&invv)[rg] * 10.0f;  // (1/tau)/||f||
            const int   lab   = ((const int*)&labv)[rg];
            float v[6];
            v[0]=acc0[rg]*scale; v[1]=acc1[rg]*scale; v[2]=acc2[rg]*scale;
            v[3]=acc3[rg]*scale; v[4]=acc4[rg]*scale; v[5]=acc5[rg]*scale;
            if (col0 >= 11) v[5] = -1e30f;            // classes 91..95 padding
            float mx = v[0];
            #pragma unroll
            for (int t = 1; t < 6; ++t) mx = fmaxf(mx, v[t]);
            #pragma unroll
            for (int o = 1; o < 16; o <<= 1) mx = fmaxf(mx, __shfl_xor(mx, o, 64));
            float se = 0.0f, ll = 0.0f;
            #pragma unroll
            for (int t = 0; t < 6; ++t) {
                se += __expf(v[t] - mx);
                if (t * 16 + col0 == lab) ll = v[t];
            }
            #pragma unroll
            for (int o = 1; o < 16; o <<= 1) {
                se += __shfl_xor(se, o, 64);
                ll += __shfl_xor(ll, o, 64);
            }
            if (col0 == 0) contrib += (mx + __logf(se) - ll) * wv[lab];
        }
    }
    contrib = wave_sum(contrib);
    if (lane == 0) unsafeAtomicAdd(pull, contrib);
}

// ---------- k6: combine ----------
__global__ void k6_final(const float* __restrict__ pull, const float* __restrict__ nvp,
                         const float* __restrict__ reps, const float* __restrict__ npr,
                         float* __restrict__ out)
{
    const float np = npr[0];
    const float rep = (np > 0.0f) ? (reps[0] / fmaxf(np, 1.0f)) : 0.0f;
    out[0] = pull[0] / nvp[0] + 0.1f * rep;
}

extern "C" void kernel_launch(void* const* d_in, const int* in_sizes, int n_in,
                              void* d_out, int out_size, void* d_ws, size_t ws_size,
                              hipStream_t stream)
{
    const float* features = (const float*)d_in[0];
    const int*   labels   = (const int*)d_in[1];
    const float* proto    = (const float*)d_in[2];
    const int*   pinit    = (const int*)d_in[3];   // bool array arrives as int32
    const int*   pcount   = (const int*)d_in[4];
    const float* pvar     = (const float*)d_in[5];
    const int*   stepp    = (const int*)d_in[6];
    float*       out      = (float*)d_out;
    const int M = in_sizes[0] / DDIM;

    // workspace layout (16B-aligned where vector-loaded)
    float* W = (float*)d_ws;
    float*        seg  = W;                                   // 23296 (16B aligned)
    unsigned int* cnt  = (unsigned int*)(seg + CDIM * DDIM);  // 91
    float*        pull = (float*)(cnt + CDIM);                // 1
    float*        reps = pull + 1;                            // 1   [zero through here]
    float*        pn   = W + 23392;                           // 23296, 16B aligned
    float*        inv  = pn + CDIM * DDIM;                    // M,   16B aligned
    float*        wv   = inv + M;                             // 91
    float*        ncnt = wv + CDIM;                           // 91
    float*        nvar = ncnt + CDIM;                         // 91
    float*        nvp  = nvar + CDIM;                         // 1
    float*        npr  = nvp + 1;                             // 1
    int*          nini = (int*)(npr + 1);                     // 91
    unsigned short* bfrag = (unsigned short*)
        (((uintptr_t)(nini + CDIM) + 255) & ~(uintptr_t)255); // 2*NFRAG bf16, 256B aligned

    hipMemsetAsync(seg, 0, (CDIM * DDIM + CDIM + 2) * sizeof(float), stream);

    k1_fused<<<256, 1024, 0, stream>>>(features, labels, inv, cnt, seg, M);
    k2_update<<<(CDIM + 3) / 4, 256, 0, stream>>>(seg, cnt, proto, pinit, pcount,
                                                  pvar, stepp, pn, ncnt, nvar, nini);
    k2b_bfrag<<<48, 64, 0, stream>>>(pn, bfrag);
    k3_weights<<<1, 128, 0, stream>>>(cnt, ncnt, nvar, nini, wv, nvp, npr);
    k4_rep<<<64, 256, 0, stream>>>(pn, nini, reps);
    k5_mfma<<<256, 1024, 0, stream>>>(features, labels, bfrag, inv, wv, pull, M);
    k6_final<<<1, 1, 0, stream>>>(pull, nvp, reps, npr, out);
}

// Round 7
// 1107.373 us; speedup vs baseline: 1.4656x; 1.0279x over previous
//
#include <hip/hip_runtime.h>
#include <hip/hip_bf16.h>
#include <math.h>
#include <stdint.h>

#define CDIM 91
#define DDIM 256
#define CPAD 96                 // 6 tiles of 16 classes
#define NFRAG 24576             // 6 tiles * 8 ksteps * 64 lanes * 8 elems (bf16 each)
#define SEGN (CDIM * DDIM)      // 23296

typedef float f32x4 __attribute__((ext_vector_type(4)));
typedef short v8s   __attribute__((ext_vector_type(8)));   // 8 bf16 in 4 VGPRs

// ---------- helpers ----------
__device__ __forceinline__ float wave_sum(float v) {
    #pragma unroll
    for (int off = 32; off > 0; off >>= 1)
        v += __shfl_xor(v, off, 64);
    return v;
}

// 4 independent butterflies interleaved: pipelines the cross-lane latency
__device__ __forceinline__ void wave_sum4(float& a, float& b, float& c, float& d) {
    #pragma unroll
    for (int off = 32; off > 0; off >>= 1) {
        a += __shfl_xor(a, off, 64);
        b += __shfl_xor(b, off, 64);
        c += __shfl_xor(c, off, 64);
        d += __shfl_xor(d, off, 64);
    }
}

__device__ __forceinline__ float block_sum128(volatile float* red, int t, float v) {
    red[t] = v;
    __syncthreads();
    for (int s = 64; s > 0; s >>= 1) {
        if (t < s) red[t] += red[t + s];
        __syncthreads();
    }
    float r = red[0];
    __syncthreads();
    return r;
}

__device__ __forceinline__ unsigned short f2bf(float x) {   // RNE f32->bf16
    union { float f; unsigned u; } a; a.f = x;
    unsigned r = a.u + 0x7fff + ((a.u >> 16) & 1);
    return (unsigned short)(r >> 16);
}
__device__ __forceinline__ float bf2f(unsigned short h) {
    union { unsigned u; float f; } a; a.u = ((unsigned)h) << 16; return a.f;
}

// ---------- k1: fused norm + histogram + scatter, 4-row ILP ----------
// Wave processes 4 rows/iter: 16 independent dword loads up front (4x the
// memory-level parallelism of 1-row-at-a-time), interleaved butterflies,
// then 16 conflict-free LDS atomics (addr = c*256 + lane + 64*q: bank =
// lane%32, 2 lanes/bank = free). Flush: plain stores to a per-block partial
// slice (k1b reduces) instead of 6M device-scope atomics; falls back to
// atomics if ws_size is too small (decision is call-invariant -> graph-safe).
__global__ __launch_bounds__(1024, 4) void k1_fused(
    const float* __restrict__ f, const int* __restrict__ labels,
    float* __restrict__ inv, unsigned int* __restrict__ cnt,
    float* __restrict__ seg, float* __restrict__ part, int usePart, int M)
{
    __shared__ float acc[SEGN];          // 93184 B
    __shared__ unsigned int hist[CDIM];
    for (int t = threadIdx.x; t < SEGN; t += 1024) acc[t] = 0.0f;
    if (threadIdx.x < CDIM) hist[threadIdx.x] = 0;
    __syncthreads();
    const int sub = threadIdx.x >> 6, lane = threadIdx.x & 63;
    const int r0 = blockIdx.x * (M / gridDim.x);     // 1024 rows/block
    for (int j = 0; j < 16; ++j) {
        const int base = r0 + sub + 64 * j;          // rows base,+16,+32,+48
        const float* fA = f + (size_t)base * DDIM;
        const float* fB = fA + 16 * DDIM;
        const float* fC = fA + 32 * DDIM;
        const float* fD = fA + 48 * DDIM;
        const float a0 = fA[lane], a1 = fA[lane+64], a2 = fA[lane+128], a3 = fA[lane+192];
        const float b0 = fB[lane], b1 = fB[lane+64], b2 = fB[lane+128], b3 = fB[lane+192];
        const float c0 = fC[lane], c1 = fC[lane+64], c2 = fC[lane+128], c3 = fC[lane+192];
        const float d0 = fD[lane], d1 = fD[lane+64], d2 = fD[lane+128], d3 = fD[lane+192];
        float sA = a0*a0 + a1*a1 + a2*a2 + a3*a3;
        float sB = b0*b0 + b1*b1 + b2*b2 + b3*b3;
        float sC = c0*c0 + c1*c1 + c2*c2 + c3*c3;
        float sD = d0*d0 + d1*d1 + d2*d2 + d3*d3;
        wave_sum4(sA, sB, sC, sD);
        const float ivA = 1.0f / fmaxf(sqrtf(sA), 1e-12f);
        const float ivB = 1.0f / fmaxf(sqrtf(sB), 1e-12f);
        const float ivC = 1.0f / fmaxf(sqrtf(sC), 1e-12f);
        const float ivD = 1.0f / fmaxf(sqrtf(sD), 1e-12f);
        const int cA = labels[base],      cB = labels[base + 16];
        const int cC = labels[base + 32], cD = labels[base + 48];
        if (lane == 0) {
            inv[base] = ivA; inv[base+16] = ivB; inv[base+32] = ivC; inv[base+48] = ivD;
            atomicAdd(&hist[cA], 1u); atomicAdd(&hist[cB], 1u);
            atomicAdd(&hist[cC], 1u); atomicAdd(&hist[cD], 1u);
        }
        float* pA = acc + cA * DDIM + lane;
        atomicAdd(pA,       a0 * ivA); atomicAdd(pA + 64,  a1 * ivA);
        atomicAdd(pA + 128, a2 * ivA); atomicAdd(pA + 192, a3 * ivA);
        float* pB = acc + cB * DDIM + lane;
        atomicAdd(pB,       b0 * ivB); atomicAdd(pB + 64,  b1 * ivB);
        atomicAdd(pB + 128, b2 * ivB); atomicAdd(pB + 192, b3 * ivB);
        float* pC = acc + cC * DDIM + lane;
        atomicAdd(pC,       c0 * ivC); atomicAdd(pC + 64,  c1 * ivC);
        atomicAdd(pC + 128, c2 * ivC); atomicAdd(pC + 192, c3 * ivC);
        float* pD = acc + cD * DDIM + lane;
        atomicAdd(pD,       d0 * ivD); atomicAdd(pD + 64,  d1 * ivD);
        atomicAdd(pD + 128, d2 * ivD); atomicAdd(pD + 192, d3 * ivD);
    }
    __syncthreads();
    if (usePart) {
        float* dst = part + (size_t)blockIdx.x * SEGN;
        for (int i = threadIdx.x; i < SEGN; i += 1024) dst[i] = acc[i];
    } else {
        for (int i = threadIdx.x; i < SEGN; i += 1024) unsafeAtomicAdd(&seg[i], acc[i]);
    }
    if (threadIdx.x < CDIM && hist[threadIdx.x])
        atomicAdd(&cnt[threadIdx.x], hist[threadIdx.x]);
}

// ---------- k1b: reduce 256 partials -> seg ----------
// Grid 728 = 91 element-blocks x 8 b-chunks; each thread sums 32 partials
// (unrolled 8 for ILP) and atomically adds into memset-zeroed seg.
__global__ __launch_bounds__(256) void k1b_reduce(
    const float* __restrict__ part, float* __restrict__ seg)
{
    const int i = (blockIdx.x >> 3) * 256 + threadIdx.x;   // [0, 23296)
    const int b0 = (blockIdx.x & 7) * 32;
    float s = 0.0f;
    #pragma unroll 8
    for (int b = b0; b < b0 + 32; ++b)
        s += part[(size_t)b * SEGN + i];
    unsafeAtomicAdd(&seg[i], s);
}

// ---------- k2: per-class EMA update + normalized prototypes ----------
__global__ __launch_bounds__(256) void k2_update(
    const float* __restrict__ seg, const unsigned int* __restrict__ cnt,
    const float* __restrict__ proto, const int* __restrict__ pinit,  // bool as int32
    const int* __restrict__ pcount, const float* __restrict__ pvar,
    const int* __restrict__ stepp,
    float* __restrict__ pn, float* __restrict__ ncnt, float* __restrict__ nvar,
    int* __restrict__ ninit)
{
    const int wid = threadIdx.x >> 6, lane = threadIdx.x & 63;
    const int c = blockIdx.x * 4 + wid;
    if (c >= CDIM) return;
    const int d0 = lane * 4;
    const float4 s = *reinterpret_cast<const float4*>(seg + c * DDIM + d0);
    const float4 p = *reinterpret_cast<const float4*>(proto + c * DDIM + d0);
    const float cntf = (float)cnt[c];
    const bool has  = cntf > 0.0f;
    const bool init = pinit[c] != 0;
    const double prog = fmin(1.0, (double)stepp[0] / 2000.0);
    const double md = 0.99 + (0.999 - 0.99) * prog;
    const float m  = (float)md, om = (float)(1.0 - md);
    const float dn = fmaxf(cntf, 1.0f);
    const float mx = s.x / dn, my = s.y / dn, mz = s.z / dn, mw = s.w / dn;
    const float ex = m * p.x + om * mx, ey = m * p.y + om * my;
    const float ez = m * p.z + om * mz, ew = m * p.w + om * mw;
    const float nx = has ? (init ? ex : mx) : p.x;
    const float ny = has ? (init ? ey : my) : p.y;
    const float nz = has ? (init ? ez : mz) : p.z;
    const float nw = has ? (init ? ew : mw) : p.w;
    const float dx = mx - p.x, dy = my - p.y, dz = mz - p.z, dw = mw - p.w;
    const float dsum = wave_sum(dx*dx + dy*dy + dz*dz + dw*dw);
    const float nsum = wave_sum(nx*nx + ny*ny + nz*nz + nw*nw);
    const float mag = sqrtf(dsum);
    const float nrm = fmaxf(sqrtf(nsum), 1e-12f);
    float4 o; o.x = nx/nrm; o.y = ny/nrm; o.z = nz/nrm; o.w = nw/nrm;
    *reinterpret_cast<float4*>(pn + c * DDIM + d0) = o;
    if (lane == 0) {
        ncnt[c]  = (float)(pcount[c] + (has ? 1 : 0));
        nvar[c]  = (has && init) ? (0.99f * pvar[c] + 0.01f * mag) : pvar[c];
        ninit[c] = (init || has) ? 1 : 0;
    }
}

// ---------- k2b: prototypes -> fragment-ordered bf16 hi/lo arrays ----------
// Element (t,s,lane,j): class c = t*16+(lane&15), k = s*32+(lane>>4)*8+j.
__global__ __launch_bounds__(64) void k2b_bfrag(
    const float* __restrict__ pn, unsigned short* __restrict__ bf)
{
    const int t = blockIdx.x >> 3, s = blockIdx.x & 7;
    const int l = threadIdx.x;
    const int c = t * 16 + (l & 15);
    const int k0 = s * 32 + (l >> 4) * 8;
    float v[8];
    if (c < CDIM) {
        const float4 x = *reinterpret_cast<const float4*>(pn + c * DDIM + k0);
        const float4 y = *reinterpret_cast<const float4*>(pn + c * DDIM + k0 + 4);
        v[0]=x.x; v[1]=x.y; v[2]=x.z; v[3]=x.w; v[4]=y.x; v[5]=y.y; v[6]=y.z; v[7]=y.w;
    } else {
        #pragma unroll
        for (int j = 0; j < 8; ++j) v[j] = 0.0f;
    }
    union { unsigned short u[8]; v8s vv; } H, L;
    #pragma unroll
    for (int j = 0; j < 8; ++j) {
        H.u[j] = f2bf(v[j]);
        L.u[j] = f2bf(v[j] - bf2f(H.u[j]));
    }
    const int base = ((t * 8 + s) * 64 + l) * 8;
    *reinterpret_cast<v8s*>(bf + base)         = H.vv;
    *reinterpret_cast<v8s*>(bf + NFRAG + base) = L.vv;
}

// ---------- k3: per-class weights ----------
__global__ __launch_bounds__(128) void k3_weights(
    const unsigned int* __restrict__ cnt, const float* __restrict__ ncnt,
    const float* __restrict__ nvar, const int* __restrict__ ninit,
    float* __restrict__ wv, float* __restrict__ nvp, float* __restrict__ npr)
{
    __shared__ float red[128];
    const int t = threadIdx.x;
    float n_c = 0.0f, fc = 0.0f, qc = 0.0f, validc = 0.0f, initc = 0.0f;
    if (t < CDIM) {
        n_c = (float)cnt[t];
        initc = ninit[t] ? 1.0f : 0.0f;
        validc = initc;
        fc = 1.0f / fmaxf(ncnt[t], 1.0f);
        qc = 1.0f / fmaxf(nvar[t], 1e-4f);
    }
    const float nv    = fmaxf(block_sum128(red, t, n_c * validc), 1e-8f);
    const float meanf = block_sum128(red, t, n_c * validc * fc) / nv;
    const float meanq = block_sum128(red, t, n_c * validc * qc) / nv;
    const float fn = fminf(fc / fmaxf(meanf, 1e-8f), 5.0f);
    const float qn = fminf(qc / fmaxf(meanq, 1e-8f), 5.0f);
    const float w  = fn * qn;
    const float meanw = block_sum128(red, t, n_c * validc * w) / nv;
    const float wn = w / fmaxf(meanw, 1e-8f);
    if (t < CDIM) wv[t] = wn * validc;
    const float ki = block_sum128(red, t, initc);
    if (t == 0) { nvp[0] = nv; npr[0] = ki * (ki - 1.0f) * 0.5f; }
}

// ---------- k4: repulsion ----------
__global__ __launch_bounds__(256) void k4_rep(
    const float* __restrict__ pn, const int* __restrict__ ninit,
    float* __restrict__ reps)
{
    const int wid = threadIdx.x >> 6, lane = threadIdx.x & 63;
    const int gw = blockIdx.x * 4 + wid;
    const int nw = gridDim.x * 4;
    for (int p = gw; p < CDIM * CDIM; p += nw) {
        const int i = p / CDIM, j = p % CDIM;
        if (i >= j) continue;
        if (!(ninit[i] && ninit[j])) continue;
        const float4 a = *reinterpret_cast<const float4*>(pn + i * DDIM + lane * 4);
        const float4 b = *reinterpret_cast<const float4*>(pn + j * DDIM + lane * 4);
        float d = a.x*b.x + a.y*b.y + a.z*b.z + a.w*b.w;
        d = wave_sum(d);
        if (lane == 0) unsafeAtomicAdd(reps, fmaxf(d, 0.0f));
    }
}

// ---------- k5: pull loss via split-bf16 MFMA + fused softmax ----------
// f32 logits emulated as fHi*pHi + fHi*pLo + fLo*pHi (err ~2^-18 rel).
// LDS (98 KB) caps at 1 block/CU = 4 waves/SIMD, so (1024,4) -> 128-VGPR
// budget: no spills (round-5's 64-VGPR cap spilled 338 MB to scratch).
__global__ __launch_bounds__(1024, 4) void k5_mfma(
    const float* __restrict__ f, const int* __restrict__ labels,
    const unsigned short* __restrict__ bfg, const float* __restrict__ inv,
    const float* __restrict__ wv, float* __restrict__ pull, int M)
{
    __shared__ __align__(16) unsigned short bl[2 * NFRAG];   // 98304 B
    {   // stage fragment-ordered B (hi|lo) linearly: conflict-free, coalesced
        const float4* src = reinterpret_cast<const float4*>(bfg);
        float4* dst = reinterpret_cast<float4*>(bl);
        #pragma unroll
        for (int i = 0; i < 6; ++i)
            dst[threadIdx.x + i * 1024] = src[threadIdx.x + i * 1024];
    }
    __syncthreads();
    const int w = threadIdx.x >> 6, lane = threadIdx.x & 63;
    const int col0 = lane & 15, grp = lane >> 4;
    const int ntiles = M / 256;                       // 1024
    float contrib = 0.0f;

    for (int tile = blockIdx.x; tile < ntiles; tile += gridDim.x) {
        const int r0 = tile * 256 + w * 16;
        const float* frow = f + (size_t)(r0 + col0) * DDIM + grp * 8;
        f32x4 acc0 = {0,0,0,0}, acc1 = {0,0,0,0}, acc2 = {0,0,0,0};
        f32x4 acc3 = {0,0,0,0}, acc4 = {0,0,0,0}, acc5 = {0,0,0,0};
        #pragma unroll
        for (int s = 0; s < 8; ++s) {
            const float4 x = *reinterpret_cast<const float4*>(frow + s * 32);
            const float4 y = *reinterpret_cast<const float4*>(frow + s * 32 + 4);
            const float v[8] = {x.x, x.y, x.z, x.w, y.x, y.y, y.z, y.w};
            union { unsigned short u[8]; v8s vv; } AH, AL;
            #pragma unroll
            for (int j = 0; j < 8; ++j) {
                AH.u[j] = f2bf(v[j]);
                AL.u[j] = f2bf(v[j] - bf2f(AH.u[j]));
            }
            #pragma unroll
            for (int t = 0; t < 6; ++t) {
                const int off = ((t * 8 + s) * 64 + lane) * 8;
                const v8s BH = *reinterpret_cast<const v8s*>(bl + off);
                const v8s BL = *reinterpret_cast<const v8s*>(bl + NFRAG + off);
                f32x4 a = (t==0)?acc0:(t==1)?acc1:(t==2)?acc2:(t==3)?acc3:(t==4)?acc4:acc5;
                a = __builtin_amdgcn_mfma_f32_16x16x32_bf16(AH.vv, BH, a, 0, 0, 0);
                a = __builtin_amdgcn_mfma_f32_16x16x32_bf16(AH.vv, BL, a, 0, 0, 0);
                a = __builtin_amdgcn_mfma_f32_16x16x32_bf16(AL.vv, BH, a, 0, 0, 0);
                if (t==0) acc0=a; else if (t==1) acc1=a; else if (t==2) acc2=a;
                else if (t==3) acc3=a; else if (t==4) acc4=a; else acc5=a;
            }
        }
        // epilogue: C/D layout col=lane&15, row=(lane>>4)*4+reg  [m89]
        const int rbase = r0 + grp * 4;
        const float4 invv = *reinterpret_cast<const float4*>(inv + rbase);
        const int4   labv = *reinterpret_cast<const int4*>(labels + rbase);
        #pragma unroll
        for (int rg = 0; rg < 4; ++rg) {
            const float scale = ((const float*)&invv)[rg] * 10.0f;  // (1/tau)/||f||
            const int   lab   = ((const int*)&labv)[rg];
            float v[6];
            v[0]=acc0[rg]*scale; v[1]=acc1[rg]*scale; v[2]=acc2[rg]*scale;
            v[3]=acc3[rg]*scale; v[4]=acc4[rg]*scale; v[5]=acc5[rg]*scale;
            if (col0 >= 11) v[5] = -1e30f;            // classes 91..95 padding
            float mx = v[0];
            #pragma unroll
            for (int t = 1; t < 6; ++t) mx = fmaxf(mx, v[t]);
            #pragma unroll
            for (int o = 1; o < 16; o <<= 1) mx = fmaxf(mx, __shfl_xor(mx, o, 64));
            float se = 0.0f, ll = 0.0f;
            #pragma unroll
            for (int t = 0; t < 6; ++t) {
                se += __expf(v[t] - mx);
                if (t * 16 + col0 == lab) ll = v[t];
            }
            #pragma unroll
            for (int o = 1; o < 16; o <<= 1) {
                se += __shfl_xor(se, o, 64);
                ll += __shfl_xor(ll, o, 64);
            }
            if (col0 == 0) contrib += (mx + __logf(se) - ll) * wv[lab];
        }
    }
    contrib = wave_sum(contrib);
    if (lane == 0) unsafeAtomicAdd(pull, contrib);
}

// ---------- k6: combine ----------
__global__ void k6_final(const float* __restrict__ pull, const float* __restrict__ nvp,
                         const float* __restrict__ reps, const float* __restrict__ npr,
                         float* __restrict__ out)
{
    const float np = npr[0];
    const float rep = (np > 0.0f) ? (reps[0] / fmaxf(np, 1.0f)) : 0.0f;
    out[0] = pull[0] / nvp[0] + 0.1f * rep;
}

extern "C" void kernel_launch(void* const* d_in, const int* in_sizes, int n_in,
                              void* d_out, int out_size, void* d_ws, size_t ws_size,
                              hipStream_t stream)
{
    const float* features = (const float*)d_in[0];
    const int*   labels   = (const int*)d_in[1];
    const float* proto    = (const float*)d_in[2];
    const int*   pinit    = (const int*)d_in[3];   // bool array arrives as int32
    const int*   pcount   = (const int*)d_in[4];
    const float* pvar     = (const float*)d_in[5];
    const int*   stepp    = (const int*)d_in[6];
    float*       out      = (float*)d_out;
    const int M = in_sizes[0] / DDIM;

    // workspace layout (16B-aligned where vector-loaded)
    float* W = (float*)d_ws;
    float*        seg  = W;                                   // 23296 (16B aligned)
    unsigned int* cnt  = (unsigned int*)(seg + SEGN);         // 91
    float*        pull = (float*)(cnt + CDIM);                // 1
    float*        reps = pull + 1;                            // 1   [zero through here]
    float*        pn   = W + 23392;                           // 23296, 16B aligned
    float*        inv  = pn + SEGN;                           // M,   16B aligned
    float*        wv   = inv + M;                             // 91
    float*        ncnt = wv + CDIM;                           // 91
    float*        nvar = ncnt + CDIM;                         // 91
    float*        nvp  = nvar + CDIM;                         // 1
    float*        npr  = nvp + 1;                             // 1
    int*          nini = (int*)(npr + 1);                     // 91
    unsigned short* bfrag = (unsigned short*)
        (((uintptr_t)(nini + CDIM) + 255) & ~(uintptr_t)255); // 2*NFRAG bf16
    float* part = (float*)
        (((uintptr_t)(bfrag + 2 * NFRAG) + 255) & ~(uintptr_t)255);
    const size_t part_bytes = (size_t)256 * SEGN * sizeof(float);   // 23.9 MB
    const size_t part_off   = (size_t)((char*)part - (char*)d_ws);
    const int usePart = (ws_size >= part_off + part_bytes) ? 1 : 0;

    hipMemsetAsync(seg, 0, (SEGN + CDIM + 2) * sizeof(float), stream);

    k1_fused<<<256, 1024, 0, stream>>>(features, labels, inv, cnt, seg, part, usePart, M);
    if (usePart)
        k1b_reduce<<<728, 256, 0, stream>>>(part, seg);
    k2_update<<<(CDIM + 3) / 4, 256, 0, stream>>>(seg, cnt, proto, pinit, pcount,
                                                  pvar, stepp, pn, ncnt, nvar, nini);
    k2b_bfrag<<<48, 64, 0, stream>>>(pn, bfrag);
    k3_weights<<<1, 128, 0, stream>>>(cnt, ncnt, nvar, nini, wv, nvp, npr);
    k4_rep<<<64, 256, 0, stream>>>(pn, nini, reps);
    k5_mfma<<<256, 1024, 0, stream>>>(features, labels, bfrag, inv, wv, pull, M);
    k6_final<<<1, 1, 0, stream>>>(pull, nvp, reps, npr, out);
}